// Round 3
// baseline (838.546 us; speedup 1.0000x reference)
//
#include <hip/hip_runtime.h>
#include <hip/hip_bf16.h>
#include <hip/hip_fp16.h>

#define N_NODES 20000
#define E_EDGES 320000
#define CIN 128
#define HDIM 128
#define EDGE_DIM 16
#define SDIM 3
#define KS 3
#define KK 27           // 3^3 kernel weight matrices
#define NB 28           // 27 spline blocks + 1 root-weight block
#define KSTEPS 112      // NB*128/32 k-steps of the fused GEMM
#define TLD (KK * 128)  // node-major T leading dim = 3456 shorts (root not stored)
#define MLP_HID 6

typedef __attribute__((ext_vector_type(8))) short v8s;   // 8 bf16 (4 VGPRs)
typedef __attribute__((ext_vector_type(4))) float v4f;   // MFMA accumulator
typedef unsigned short ush;

static __device__ __forceinline__ short f2bf(float v) {
    unsigned u = __float_as_uint(v);
    unsigned r = (u + 0x7fffu + ((u >> 16) & 1u)) >> 16;   // RTNE
    return (short)r;
}
static __device__ __forceinline__ float bf2f_lo(unsigned u) {   // low short
    return __uint_as_float(u << 16);
}
static __device__ __forceinline__ float bf2f_hi(unsigned u) {   // high short
    return __uint_as_float(u & 0xffff0000u);
}
static __device__ __forceinline__ unsigned pack2bf(float a, float b) {
    return ((unsigned)(ush)f2bf(a)) | (((unsigned)(ush)f2bf(b)) << 16);
}

// ---------------------------------------------------------------------------
// edge_index dtype detect + decode (int64 vs int32 storage)
// ---------------------------------------------------------------------------
__global__ void detect_kernel(const unsigned int* __restrict__ e, int* __restrict__ flag) {
    __shared__ int s_nz;
    if (threadIdx.x == 0) s_nz = 0;
    __syncthreads();
    unsigned int v = e[threadIdx.x * 2 + 1];
    if (v != 0) atomicAdd(&s_nz, 1);
    __syncthreads();
    if (threadIdx.x == 0) *flag = (s_nz > 0) ? 1 : 0;
}

__global__ void decode_edges(const void* __restrict__ eraw, const int* __restrict__ flag,
                             int* __restrict__ e32, int n) {
    int i = blockIdx.x * blockDim.x + threadIdx.x;
    if (i >= n) return;
    if (*flag) e32[i] = ((const int*)eraw)[i];
    else       e32[i] = (int)(((const long long*)eraw)[i]);
}

// ---------------------------------------------------------------------------
// Edge MLP (16->6 relu ->3 sigmoid) -> (frac[3], lo[3]) per edge, packed 16 B.
// ---------------------------------------------------------------------------
__global__ void edge_basis(const float* __restrict__ ea,
                           const float* __restrict__ Wp1, const float* __restrict__ bp1,
                           const float* __restrict__ Wp2, const float* __restrict__ bp2,
                           float4* __restrict__ fb) {
    __shared__ float sW1[EDGE_DIM * MLP_HID];
    __shared__ float sb1[MLP_HID];
    __shared__ float sW2[MLP_HID * SDIM];
    __shared__ float sb2[SDIM];
    int t = threadIdx.x;
    if (t < EDGE_DIM * MLP_HID) sW1[t] = Wp1[t];
    if (t < MLP_HID)            sb1[t] = bp1[t];
    if (t < MLP_HID * SDIM)     sW2[t] = Wp2[t];
    if (t < SDIM)               sb2[t] = bp2[t];
    __syncthreads();
    int e = blockIdx.x * blockDim.x + t;
    if (e >= E_EDGES) return;

    float a[EDGE_DIM];
#pragma unroll
    for (int i = 0; i < EDGE_DIM; i++) a[i] = ea[(long)e * EDGE_DIM + i];

    float hid[MLP_HID];
#pragma unroll
    for (int j = 0; j < MLP_HID; j++) {
        float s = sb1[j];
#pragma unroll
        for (int i = 0; i < EDGE_DIM; i++) s += a[i] * sW1[i * MLP_HID + j];
        hid[j] = fmaxf(s, 0.f);
    }

    float fr[SDIM];
    unsigned lp = 0;
#pragma unroll
    for (int d = 0; d < SDIM; d++) {
        float s = sb2[d];
#pragma unroll
        for (int j = 0; j < MLP_HID; j++) s += hid[j] * sW2[j * SDIM + d];
        float u = 1.f / (1.f + expf(-s));
        float v = u * (float)(KS - 1);
        float l = floorf(v);
        l = fminf(fmaxf(l, 0.f), (float)(KS - 2));
        fr[d] = v - l;
        lp |= ((unsigned)(int)l) << (8 * d);
    }
    float4 o;
    o.x = fr[0]; o.y = fr[1]; o.z = fr[2]; o.w = __uint_as_float(lp);
    fb[e] = o;
}

// ---------------------------------------------------------------------------
// CSR build binned by dst — built once, reused for 3 layers
// ---------------------------------------------------------------------------
__global__ void zero_int(int* __restrict__ p, int n) {
    int i = blockIdx.x * blockDim.x + threadIdx.x;
    if (i < n) p[i] = 0;
}

__global__ void hist_kernel(const int* __restrict__ dst, int* __restrict__ hist) {
    int e = blockIdx.x * blockDim.x + threadIdx.x;
    if (e >= E_EDGES) return;
    atomicAdd(&hist[dst[e]], 1);
}

__global__ void scan_kernel(const int* __restrict__ hist, int* __restrict__ rowptr, int B) {
    __shared__ int part[256];
    int t = threadIdx.x;
    const int per = (B + 255) / 256;
    int base = t * per;
    int s = 0;
    for (int i = 0; i < per; i++) {
        int idx = base + i;
        if (idx < B) s += hist[idx];
    }
    part[t] = s;
    __syncthreads();
    for (int off = 1; off < 256; off <<= 1) {
        int v = (t >= off) ? part[t - off] : 0;
        __syncthreads();
        part[t] += v;
        __syncthreads();
    }
    int run = (t == 0) ? 0 : part[t - 1];
    for (int i = 0; i < per; i++) {
        int idx = base + i;
        if (idx < B) { rowptr[idx] = run; run += hist[idx]; }
    }
    if (t == 255) rowptr[B] = run;
}

__global__ void perm_kernel(const int* __restrict__ dst,
                            const int* __restrict__ rowptr, int* __restrict__ cursor,
                            int* __restrict__ eperm) {
    int e = blockIdx.x * blockDim.x + threadIdx.x;
    if (e >= E_EDGES) return;
    int bin = dst[e];
    int pos = rowptr[bin] + atomicAdd(&cursor[bin], 1);
    eperm[pos] = e;
}

// ---------------------------------------------------------------------------
// Pack per-edge metadata into CSR order: src index + DENSE 27 spline weights
// (fp32, stride 28 floats = 112 B, float4-aligned).
// ---------------------------------------------------------------------------
__global__ void pack_w27(const int* __restrict__ eperm, const int* __restrict__ src,
                         const float4* __restrict__ fb,
                         int* __restrict__ srcp, float* __restrict__ w27p) {
    int j = blockIdx.x * blockDim.x + threadIdx.x;
    if (j >= E_EDGES) return;
    int e = eperm[j];
    srcp[j] = src[e];
    float4 f = fb[e];
    unsigned lp = __float_as_uint(f.w);
    float fr[3] = {f.x, f.y, f.z};
    float t[3][3];
#pragma unroll
    for (int d = 0; d < 3; d++) {
        int lo = (lp >> (8 * d)) & 255;
        float fd = fr[d];
#pragma unroll
        for (int q = 0; q < 3; q++)
            t[d][q] = (q == lo) ? (1.f - fd) : (q == lo + 1) ? fd : 0.f;
    }
    float out[28];
#pragma unroll
    for (int k2 = 0; k2 < 3; k2++)
#pragma unroll
        for (int k1 = 0; k1 < 3; k1++)
#pragma unroll
            for (int k0 = 0; k0 < 3; k0++)
                out[k2 * 9 + k1 * 3 + k0] = t[0][k0] * t[1][k1] * t[2][k2];
    out[27] = 0.f;
    float* op = w27p + (size_t)j * 28;
#pragma unroll
    for (int q = 0; q < 7; q++) *(float4*)(op + 4 * q) = *(float4*)(out + 4 * q);
}

// ---------------------------------------------------------------------------
// Pack [W (27 blocks) | Wr] of ALL 3 LAYERS -> bf16 MFMA B-fragment layout.
// Layout [layer][flat_ks=kb*4+ks][nt][64][8] — one fused K=3584 B panel.
// ---------------------------------------------------------------------------
__global__ void packW3_kernel(const float* __restrict__ W0, const float* __restrict__ Wr0,
                              const float* __restrict__ W1, const float* __restrict__ Wr1,
                              const float* __restrict__ W2, const float* __restrict__ Wr2,
                              short* __restrict__ hi) {
    int gid = blockIdx.x * blockDim.x + threadIdx.x;
    if (gid >= 3 * NB * 4 * 8 * 64) return;
    int lane = gid & 63;
    int nt = (gid >> 6) & 7;
    int ks = (gid >> 9) & 3;
    int kb2 = gid >> 11;           // 0..83
    int layer = kb2 / NB;
    int kb = kb2 - layer * NB;
    const float* W  = (layer == 0) ? W0  : (layer == 1) ? W1  : W2;
    const float* Wr = (layer == 0) ? Wr0 : (layer == 1) ? Wr1 : Wr2;
    int i0 = ks * 32 + ((lane >> 4) & 3) * 8;
    int o = nt * 16 + (lane & 15);
    const float* src = (kb < KK) ? (W + (long)kb * 16384 + (long)i0 * 128 + o)
                                 : (Wr + (long)i0 * 128 + o);
    long off = ((long)(((size_t)layer * NB + kb) * 4 + ks) * 8 + nt) * 64 * 8
             + (long)lane * 8;
#pragma unroll
    for (int j = 0; j < 8; j++) {
        float v = src[(long)j * 128];
        hi[off + j] = f2bf(v);
    }
}

// ---------------------------------------------------------------------------
// x (fp32) -> xb (bf16 row-major) once; later layers' activations are written
// bf16 row-major by the GEMM epilogue directly.
// ---------------------------------------------------------------------------
__global__ void conv_xb(const float* __restrict__ x, ush* __restrict__ xb) {
    int i = blockIdx.x * blockDim.x + threadIdx.x;
    if (i >= N_NODES * CIN / 4) return;
    float4 v = ((const float4*)x)[i];
    uint2 d;
    d.x = pack2bf(v.x, v.y);
    d.y = pack2bf(v.z, v.w);
    ((uint2*)xb)[i] = d;
}

// ---------------------------------------------------------------------------
// accumT v2: 4 waves/block (one dst node per wave, 4x occupancy ceiling vs
// 64-thread blocks). Lane owns channels (2l, 2l+1); T[dst, k, ch] lives in
// 54 fp32 registers. Per edge: prefetched srcp + act-row load for edge j+1
// issued before the 54 FMAs of edge j (breaks the srcp->act dependent-latency
// chain; ~2 edges in flight per wave). Output written NODE-MAJOR
// (T[n][k*128+ch], 256 B contiguous per (n,k)) — full-line coalesced stores,
// no cross-wave line interleaving, no write amplification.
// Root-weight block is NOT stored; gemm2 reads act directly for ks>=108.
// ---------------------------------------------------------------------------
__global__ __launch_bounds__(256) void accumT_kernel(
    const ush* __restrict__ act, const int* __restrict__ rowptr,
    const int* __restrict__ srcp, const float* __restrict__ w27p,
    ush* __restrict__ T, int n0, int nmax)
{
    int lane = threadIdx.x & 63;
    int wave = threadIdx.x >> 6;
    int n = n0 + blockIdx.x * 4 + wave;
    if (n >= nmax) return;
    int jb = rowptr[n], je = rowptr[n + 1];

    float acc[KK][2];
#pragma unroll
    for (int k = 0; k < KK; k++) { acc[k][0] = 0.f; acc[k][1] = 0.f; }

    const ush* actl = act + lane * 2;   // per-lane channel-pair base

    if (jb < je) {
        int s0 = srcp[jb];
        unsigned xcur = *(const unsigned*)(actl + (size_t)s0 * 128);
        for (int j = jb; j < je; j++) {
            int jn = j + 1 < je ? j + 1 : j;
            int sn = srcp[jn];                                     // prefetch src
            unsigned xnext = *(const unsigned*)(actl + (size_t)sn * 128); // prefetch act
            const float4* w4 = (const float4*)(w27p + (size_t)j * 28);
            float w[28];
#pragma unroll
            for (int q = 0; q < 7; q++) *(float4*)(w + 4 * q) = w4[q];
            float x0 = bf2f_lo(xcur);
            float x1 = bf2f_hi(xcur);
#pragma unroll
            for (int k = 0; k < KK; k++) {
                acc[k][0] += w[k] * x0;
                acc[k][1] += w[k] * x1;
            }
            xcur = xnext;
        }
    }

    ush* tp = T + (size_t)(n - n0) * TLD + lane * 2;
#pragma unroll
    for (int k = 0; k < KK; k++) {
        *(unsigned*)(tp + k * 128) = pack2bf(acc[k][0], acc[k][1]);
    }
}

// ---------------------------------------------------------------------------
// gemm2 v2: out[n, o] = [T_row(3456) | act_row(128)] . Wall(3584 x 128) + bias
// One m-tile (16 rows) per block -> 625 blocks/chunk (4 blocks/CU by LDS,
// ~2.4 rounds). 4 waves split K (28 k-steps each); partials reduced via LDS.
// A read node-major from T (ks<108) or row-major act (ks>=108, root weight).
// ---------------------------------------------------------------------------
__global__ __launch_bounds__(256) void gemm2_kernel(
    const ush* __restrict__ T, const ush* __restrict__ act,
    const short* __restrict__ Wh, const float* __restrict__ bias,
    ush* __restrict__ actout, float* __restrict__ fout,
    int n0, int relu)
{
    __shared__ float S[256][33];
    int lane = threadIdx.x & 63;
    int wave = threadIdx.x >> 6;
    int mtr = blockIdx.x;

    v4f acc[8];
#pragma unroll
    for (int nt = 0; nt < 8; nt++) acc[nt] = (v4f){0.f, 0.f, 0.f, 0.f};

    int arow = mtr * 16 + (lane & 15);           // chunk-local row
    int sub  = (lane >> 4) & 3;
    const ush* tp  = T + (size_t)arow * TLD + sub * 8;
    const ush* ap  = act + (size_t)(n0 + arow) * 128 + sub * 8;

    int ks0 = wave * (KSTEPS / 4);
    for (int ks = ks0; ks < ks0 + KSTEPS / 4; ks++) {
        v8s a;
        if (ks < (KK * 4)) a = *(const v8s*)(tp + ks * 32);
        else               a = *(const v8s*)(ap + (ks - KK * 4) * 32);
        const short* wb = Wh + ((size_t)ks * 8 * 64) * 8 + (size_t)lane * 8;
#pragma unroll
        for (int nt = 0; nt < 8; nt++) {
            v8s bh = *(const v8s*)(wb + (size_t)nt * 64 * 8);
            acc[nt] = __builtin_amdgcn_mfma_f32_16x16x32_bf16(a, bh, acc[nt], 0, 0, 0);
        }
    }

    // cross-wave reduce + epilogue
#pragma unroll
    for (int q = 0; q < 32; q++) S[threadIdx.x][q] = acc[q >> 2][q & 3];
    __syncthreads();

    int r  = (threadIdx.x >> 3) & 15;
    int o0 = (threadIdx.x & 7) * 16 + (threadIdx.x >> 7) * 8;
    int row = n0 + mtr * 16 + r;
    float v[8];
#pragma unroll
    for (int q = 0; q < 8; q++) {
        int o = o0 + q;
        int ln = (o & 15) + 16 * (r >> 2);       // source lane of C-frag
        int idx = (o >> 4) * 4 + (r & 3);        // nt*4 + reg
        float s = S[ln][idx] + S[64 + ln][idx] + S[128 + ln][idx] + S[192 + ln][idx];
        s += bias[o];
        if (relu) s = fmaxf(s, 0.f);
        v[q] = s;
    }
    if (actout) {
        uint4 u;
        u.x = pack2bf(v[0], v[1]);
        u.y = pack2bf(v[2], v[3]);
        u.z = pack2bf(v[4], v[5]);
        u.w = pack2bf(v[6], v[7]);
        *(uint4*)(actout + (size_t)row * 128 + o0) = u;
    } else {
        float4 f0, f1;
        f0.x = v[0]; f0.y = v[1]; f0.z = v[2]; f0.w = v[3];
        f1.x = v[4]; f1.y = v[5]; f1.z = v[6]; f1.w = v[7];
        *(float4*)(fout + (size_t)row * 128 + o0) = f0;
        *(float4*)(fout + (size_t)row * 128 + o0 + 4) = f1;
    }
}

// ---------------------------------------------------------------------------
extern "C" void kernel_launch(void* const* d_in, const int* in_sizes, int n_in,
                              void* d_out, int out_size, void* d_ws, size_t ws_size,
                              hipStream_t stream) {
    const float* x   = (const float*)d_in[0];
    const void*  eix = d_in[1];
    const float* ea  = (const float*)d_in[2];
    const float* Wp1 = (const float*)d_in[3];
    const float* bp1 = (const float*)d_in[4];
    const float* Wp2 = (const float*)d_in[5];
    const float* bp2 = (const float*)d_in[6];
    const float* W[3]  = {(const float*)d_in[7],  (const float*)d_in[10], (const float*)d_in[13]};
    const float* Wr[3] = {(const float*)d_in[8],  (const float*)d_in[11], (const float*)d_in[14]};
    const float* b[3]  = {(const float*)d_in[9],  (const float*)d_in[12], (const float*)d_in[15]};
    float* out = (float*)d_out;

    char* ws = (char*)d_ws;
    size_t off = 0;
    auto walloc = [&](size_t bytes) -> void* {
        void* p = ws + off;
        off = (off + bytes + 255) & ~(size_t)255;
        return p;
    };
    int*    flag    = (int*)   walloc(sizeof(int));
    int*    e32     = (int*)   walloc(sizeof(int) * 2 * E_EDGES);
    float4* fb      = (float4*)walloc(sizeof(float4) * (size_t)E_EDGES);
    int*    srcp    = (int*)   walloc(sizeof(int) * E_EDGES);
    int*    eperm   = (int*)   walloc(sizeof(int) * E_EDGES);
    float*  w27p    = (float*) walloc(sizeof(float) * (size_t)E_EDGES * 28);
    int*    histcur = (int*)   walloc(sizeof(int) * (size_t)N_NODES * 2);
    int*    rowptr  = (int*)   walloc(sizeof(int) * (N_NODES + 1));
    ush*    xb      = (ush*)   walloc(sizeof(ush) * (size_t)N_NODES * 128);
    ush*    a1      = (ush*)   walloc(sizeof(ush) * (size_t)N_NODES * 128);
    ush*    a2      = (ush*)   walloc(sizeof(ush) * (size_t)N_NODES * 128);
    short*  Wh3     = (short*) walloc(sizeof(short) * (size_t)3 * NB * 128 * 128);

    // Runtime chunk-size fallback: T chunk must fit in the remaining ws.
    // 20000 % chunk_n == 0 and chunk_n % 16 == 0 for all candidates.
    int chunk_n = 10000;
    {
        const int cand[3] = {10000, 4000, 2000};
        for (int i = 0; i < 3; i++) {
            size_t need = (size_t)cand[i] * TLD * sizeof(ush);
            chunk_n = cand[i];
            if (off + need <= ws_size) break;
        }
    }
    ush* T = (ush*)walloc((size_t)chunk_n * TLD * sizeof(ush));

    int* srcv = e32;
    int* dstv = e32 + E_EDGES;
    int* hist   = histcur;
    int* cursor = histcur + N_NODES;

    detect_kernel<<<1, 1024, 0, stream>>>((const unsigned int*)eix, flag);
    decode_edges<<<(2 * E_EDGES + 255) / 256, 256, 0, stream>>>(eix, flag, e32, 2 * E_EDGES);
    edge_basis<<<(E_EDGES + 255) / 256, 256, 0, stream>>>(ea, Wp1, bp1, Wp2, bp2, fb);

    // CSR binned by dst; built once, reused across 3 layers
    zero_int<<<(N_NODES * 2 + 255) / 256, 256, 0, stream>>>(histcur, N_NODES * 2);
    hist_kernel<<<(E_EDGES + 255) / 256, 256, 0, stream>>>(dstv, hist);
    scan_kernel<<<1, 256, 0, stream>>>(hist, rowptr, N_NODES);
    perm_kernel<<<(E_EDGES + 255) / 256, 256, 0, stream>>>(dstv, rowptr, cursor, eperm);
    pack_w27<<<(E_EDGES + 255) / 256, 256, 0, stream>>>(eperm, srcv, fb, srcp, w27p);

    packW3_kernel<<<(3 * NB * 4 * 8 * 64 + 255) / 256, 256, 0, stream>>>(
        W[0], Wr[0], W[1], Wr[1], W[2], Wr[2], Wh3);
    conv_xb<<<(N_NODES * CIN / 4 + 255) / 256, 256, 0, stream>>>(x, xb);

    const ush* actin = xb;
    for (int l = 0; l < 3; l++) {
        const short* Wh = Wh3 + (size_t)l * NB * 128 * 128;
        ush* actout = (l == 0) ? a1 : (l == 1) ? a2 : nullptr;
        for (int n0 = 0; n0 < N_NODES; n0 += chunk_n) {
            int cn = (n0 + chunk_n <= N_NODES) ? chunk_n : (N_NODES - n0);
            int nmt = cn / 16;
            accumT_kernel<<<(cn + 3) / 4, 256, 0, stream>>>(
                actin, rowptr, srcp, w27p, T, n0, n0 + cn);
            gemm2_kernel<<<nmt, 256, 0, stream>>>(
                T, actin, Wh, b[l], actout, (l == 2) ? out : nullptr,
                n0, (l < 2) ? 1 : 0);
        }
        if (l == 0) actin = a1; else if (l == 1) actin = a2;
    }
}

// Round 4
// 755.182 us; speedup vs baseline: 1.1104x; 1.1104x over previous
//
#include <hip/hip_runtime.h>
#include <hip/hip_bf16.h>
#include <hip/hip_fp16.h>

#define N_NODES 20000
#define E_EDGES 320000
#define CIN 128
#define HDIM 128
#define EDGE_DIM 16
#define SDIM 3
#define KS 3
#define KK 27           // 3^3 kernel weight matrices
#define NB 28           // 27 spline blocks + 1 root-weight block
#define KSTEPS 112      // NB*128/32 k-steps of the fused GEMM
#define TLD (KK * 128)  // node-major T leading dim = 3456 shorts (root not stored)
#define WLD 32          // padded per-edge spline-weight stride (floats)
#define MLP_HID 6

typedef __attribute__((ext_vector_type(8))) short v8s;   // 8 bf16 (4 VGPRs)
typedef __attribute__((ext_vector_type(4))) float v4f;   // MFMA accumulator
typedef unsigned short ush;

static __device__ __forceinline__ short f2bf(float v) {
    unsigned u = __float_as_uint(v);
    unsigned r = (u + 0x7fffu + ((u >> 16) & 1u)) >> 16;   // RTNE
    return (short)r;
}
static __device__ __forceinline__ float bf2f_lo(unsigned u) {   // low short
    return __uint_as_float(u << 16);
}
static __device__ __forceinline__ float bf2f_hi(unsigned u) {   // high short
    return __uint_as_float(u & 0xffff0000u);
}
static __device__ __forceinline__ unsigned pack2bf(float a, float b) {
    return ((unsigned)(ush)f2bf(a)) | (((unsigned)(ush)f2bf(b)) << 16);
}

// ---------------------------------------------------------------------------
// edge_index dtype detect + decode (int64 vs int32 storage)
// ---------------------------------------------------------------------------
__global__ void detect_kernel(const unsigned int* __restrict__ e, int* __restrict__ flag) {
    __shared__ int s_nz;
    if (threadIdx.x == 0) s_nz = 0;
    __syncthreads();
    unsigned int v = e[threadIdx.x * 2 + 1];
    if (v != 0) atomicAdd(&s_nz, 1);
    __syncthreads();
    if (threadIdx.x == 0) *flag = (s_nz > 0) ? 1 : 0;
}

__global__ void decode_edges(const void* __restrict__ eraw, const int* __restrict__ flag,
                             int* __restrict__ e32, int n) {
    int i = blockIdx.x * blockDim.x + threadIdx.x;
    if (i >= n) return;
    if (*flag) e32[i] = ((const int*)eraw)[i];
    else       e32[i] = (int)(((const long long*)eraw)[i]);
}

// ---------------------------------------------------------------------------
// Edge MLP (16->6 relu ->3 sigmoid) -> (frac[3], lo[3]) per edge, packed 16 B.
// ---------------------------------------------------------------------------
__global__ void edge_basis(const float* __restrict__ ea,
                           const float* __restrict__ Wp1, const float* __restrict__ bp1,
                           const float* __restrict__ Wp2, const float* __restrict__ bp2,
                           float4* __restrict__ fb) {
    __shared__ float sW1[EDGE_DIM * MLP_HID];
    __shared__ float sb1[MLP_HID];
    __shared__ float sW2[MLP_HID * SDIM];
    __shared__ float sb2[SDIM];
    int t = threadIdx.x;
    if (t < EDGE_DIM * MLP_HID) sW1[t] = Wp1[t];
    if (t < MLP_HID)            sb1[t] = bp1[t];
    if (t < MLP_HID * SDIM)     sW2[t] = Wp2[t];
    if (t < SDIM)               sb2[t] = bp2[t];
    __syncthreads();
    int e = blockIdx.x * blockDim.x + t;
    if (e >= E_EDGES) return;

    float a[EDGE_DIM];
#pragma unroll
    for (int i = 0; i < EDGE_DIM; i++) a[i] = ea[(long)e * EDGE_DIM + i];

    float hid[MLP_HID];
#pragma unroll
    for (int j = 0; j < MLP_HID; j++) {
        float s = sb1[j];
#pragma unroll
        for (int i = 0; i < EDGE_DIM; i++) s += a[i] * sW1[i * MLP_HID + j];
        hid[j] = fmaxf(s, 0.f);
    }

    float fr[SDIM];
    unsigned lp = 0;
#pragma unroll
    for (int d = 0; d < SDIM; d++) {
        float s = sb2[d];
#pragma unroll
        for (int j = 0; j < MLP_HID; j++) s += hid[j] * sW2[j * SDIM + d];
        float u = 1.f / (1.f + expf(-s));
        float v = u * (float)(KS - 1);
        float l = floorf(v);
        l = fminf(fmaxf(l, 0.f), (float)(KS - 2));
        fr[d] = v - l;
        lp |= ((unsigned)(int)l) << (8 * d);
    }
    float4 o;
    o.x = fr[0]; o.y = fr[1]; o.z = fr[2]; o.w = __uint_as_float(lp);
    fb[e] = o;
}

// ---------------------------------------------------------------------------
// CSR build binned by dst — built once, reused for 3 layers
// ---------------------------------------------------------------------------
__global__ void zero_int(int* __restrict__ p, int n) {
    int i = blockIdx.x * blockDim.x + threadIdx.x;
    if (i < n) p[i] = 0;
}

__global__ void hist_kernel(const int* __restrict__ dst, int* __restrict__ hist) {
    int e = blockIdx.x * blockDim.x + threadIdx.x;
    if (e >= E_EDGES) return;
    atomicAdd(&hist[dst[e]], 1);
}

__global__ void scan_kernel(const int* __restrict__ hist, int* __restrict__ rowptr, int B) {
    __shared__ int part[256];
    int t = threadIdx.x;
    const int per = (B + 255) / 256;
    int base = t * per;
    int s = 0;
    for (int i = 0; i < per; i++) {
        int idx = base + i;
        if (idx < B) s += hist[idx];
    }
    part[t] = s;
    __syncthreads();
    for (int off = 1; off < 256; off <<= 1) {
        int v = (t >= off) ? part[t - off] : 0;
        __syncthreads();
        part[t] += v;
        __syncthreads();
    }
    int run = (t == 0) ? 0 : part[t - 1];
    for (int i = 0; i < per; i++) {
        int idx = base + i;
        if (idx < B) { rowptr[idx] = run; run += hist[idx]; }
    }
    if (t == 255) rowptr[B] = run;
}

__global__ void perm_kernel(const int* __restrict__ dst,
                            const int* __restrict__ rowptr, int* __restrict__ cursor,
                            int* __restrict__ eperm) {
    int e = blockIdx.x * blockDim.x + threadIdx.x;
    if (e >= E_EDGES) return;
    int bin = dst[e];
    int pos = rowptr[bin] + atomicAdd(&cursor[bin], 1);
    eperm[pos] = e;
}

// ---------------------------------------------------------------------------
// Pack per-edge metadata into CSR order: src index + DENSE spline weights,
// padded to 32 floats (128 B) so each of 4 k-split waves reads an aligned
// 32 B window: wave w reads floats [8w, 8w+8); floats 27..31 are zero.
// ---------------------------------------------------------------------------
__global__ void pack_w27(const int* __restrict__ eperm, const int* __restrict__ src,
                         const float4* __restrict__ fb,
                         int* __restrict__ srcp, float* __restrict__ w32p) {
    int j = blockIdx.x * blockDim.x + threadIdx.x;
    if (j >= E_EDGES) return;
    int e = eperm[j];
    srcp[j] = src[e];
    float4 f = fb[e];
    unsigned lp = __float_as_uint(f.w);
    float fr[3] = {f.x, f.y, f.z};
    float t[3][3];
#pragma unroll
    for (int d = 0; d < 3; d++) {
        int lo = (lp >> (8 * d)) & 255;
        float fd = fr[d];
#pragma unroll
        for (int q = 0; q < 3; q++)
            t[d][q] = (q == lo) ? (1.f - fd) : (q == lo + 1) ? fd : 0.f;
    }
    float out[WLD];
#pragma unroll
    for (int q = 0; q < WLD; q++) out[q] = 0.f;
#pragma unroll
    for (int k2 = 0; k2 < 3; k2++)
#pragma unroll
        for (int k1 = 0; k1 < 3; k1++)
#pragma unroll
            for (int k0 = 0; k0 < 3; k0++)
                out[k2 * 9 + k1 * 3 + k0] = t[0][k0] * t[1][k1] * t[2][k2];
    float* op = w32p + (size_t)j * WLD;
#pragma unroll
    for (int q = 0; q < WLD / 4; q++) *(float4*)(op + 4 * q) = *(float4*)(out + 4 * q);
}

// ---------------------------------------------------------------------------
// Pack [W (27 blocks) | Wr] of ALL 3 LAYERS -> bf16 MFMA B-fragment layout.
// Layout [layer][flat_ks=kb*4+ks][nt][64][8] — one fused K=3584 B panel.
// ---------------------------------------------------------------------------
__global__ void packW3_kernel(const float* __restrict__ W0, const float* __restrict__ Wr0,
                              const float* __restrict__ W1, const float* __restrict__ Wr1,
                              const float* __restrict__ W2, const float* __restrict__ Wr2,
                              short* __restrict__ hi) {
    int gid = blockIdx.x * blockDim.x + threadIdx.x;
    if (gid >= 3 * NB * 4 * 8 * 64) return;
    int lane = gid & 63;
    int nt = (gid >> 6) & 7;
    int ks = (gid >> 9) & 3;
    int kb2 = gid >> 11;           // 0..83
    int layer = kb2 / NB;
    int kb = kb2 - layer * NB;
    const float* W  = (layer == 0) ? W0  : (layer == 1) ? W1  : W2;
    const float* Wr = (layer == 0) ? Wr0 : (layer == 1) ? Wr1 : Wr2;
    int i0 = ks * 32 + ((lane >> 4) & 3) * 8;
    int o = nt * 16 + (lane & 15);
    const float* src = (kb < KK) ? (W + (long)kb * 16384 + (long)i0 * 128 + o)
                                 : (Wr + (long)i0 * 128 + o);
    long off = ((long)(((size_t)layer * NB + kb) * 4 + ks) * 8 + nt) * 64 * 8
             + (long)lane * 8;
#pragma unroll
    for (int j = 0; j < 8; j++) {
        float v = src[(long)j * 128];
        hi[off + j] = f2bf(v);
    }
}

// ---------------------------------------------------------------------------
// x (fp32) -> xb (bf16 row-major) once; later layers' activations are written
// bf16 row-major by the GEMM epilogue directly.
// ---------------------------------------------------------------------------
__global__ void conv_xb(const float* __restrict__ x, ush* __restrict__ xb) {
    int i = blockIdx.x * blockDim.x + threadIdx.x;
    if (i >= N_NODES * CIN / 4) return;
    float4 v = ((const float4*)x)[i];
    uint2 d;
    d.x = pack2bf(v.x, v.y);
    d.y = pack2bf(v.z, v.w);
    ((uint2*)xb)[i] = d;
}

// ---------------------------------------------------------------------------
// accumT v3: one block (4 waves) per dst node; wave w owns k in [8w, 8w+8)
// (k 27..31 are zero-weight pads). Lane owns channels (2l, 2l+1).
// acc is 16 fp32 registers per lane. Per edge: 1x 4B act load + 2x float4
// weight loads — ALL prefetched one edge ahead (srcp, act, weights), so no
// iteration starts with an exposed dependent-load chain. T written
// node-major, full 256 B coalesced lines per (n,k).
// ---------------------------------------------------------------------------
__global__ __launch_bounds__(256) void accumT_kernel(
    const ush* __restrict__ act, const int* __restrict__ rowptr,
    const int* __restrict__ srcp, const float* __restrict__ w32p,
    ush* __restrict__ T, int n0)
{
    int lane = threadIdx.x & 63;
    int wave = threadIdx.x >> 6;         // k-split 0..3
    int n = n0 + blockIdx.x;
    int jb = rowptr[n], je = rowptr[n + 1];

    float acc[8][2];
#pragma unroll
    for (int k = 0; k < 8; k++) { acc[k][0] = 0.f; acc[k][1] = 0.f; }

    const ush* actl = act + lane * 2;                      // channel-pair base
    const float4* wbase = (const float4*)w32p + wave * 2;  // wave's 32B window

    if (jb < je) {
        int s = srcp[jb];
        unsigned xc = *(const unsigned*)(actl + (size_t)s * 128);
        float4 wc0 = wbase[(size_t)jb * (WLD / 4)];
        float4 wc1 = wbase[(size_t)jb * (WLD / 4) + 1];
        for (int j = jb; j < je; j++) {
            int jn = (j + 1 < je) ? j + 1 : j;
            int sn = srcp[jn];                                         // prefetch
            unsigned xn = *(const unsigned*)(actl + (size_t)sn * 128); // prefetch
            float4 wn0 = wbase[(size_t)jn * (WLD / 4)];                // prefetch
            float4 wn1 = wbase[(size_t)jn * (WLD / 4) + 1];            // prefetch
            float x0 = bf2f_lo(xc);
            float x1 = bf2f_hi(xc);
            float w[8] = {wc0.x, wc0.y, wc0.z, wc0.w, wc1.x, wc1.y, wc1.z, wc1.w};
#pragma unroll
            for (int k = 0; k < 8; k++) {
                acc[k][0] += w[k] * x0;
                acc[k][1] += w[k] * x1;
            }
            xc = xn; wc0 = wn0; wc1 = wn1;
        }
    }

    ush* tp = T + (size_t)(n - n0) * TLD + lane * 2;
    int kb = wave * 8;
#pragma unroll
    for (int k = 0; k < 8; k++) {
        int kk = kb + k;
        if (kk < KK)
            *(unsigned*)(tp + (size_t)kk * 128) = pack2bf(acc[k][0], acc[k][1]);
    }
}

// ---------------------------------------------------------------------------
// gemm2 v3: out[n,o] = [T_row(3456) | act_row(128)] . Wall(3584x128) + bias
// 512 threads / 8 waves per block, ONE m-tile (16 rows); wave w owns 14
// k-steps. A + 8 B-fragments prefetched one k-step ahead. Cross-wave reduce
// through LDS in two 64-col passes (LDS 34.8 KB -> 4 blocks/CU occupancy).
// ---------------------------------------------------------------------------
__global__ __launch_bounds__(512) void gemm2_kernel(
    const ush* __restrict__ T, const ush* __restrict__ act,
    const short* __restrict__ Wh, const float* __restrict__ bias,
    ush* __restrict__ actout, float* __restrict__ fout,
    int n0, int relu)
{
    __shared__ float S[512][17];
    int lane = threadIdx.x & 63;
    int wave = threadIdx.x >> 6;
    int mtr = blockIdx.x;

    v4f acc[8];
#pragma unroll
    for (int nt = 0; nt < 8; nt++) acc[nt] = (v4f){0.f, 0.f, 0.f, 0.f};

    int arow = mtr * 16 + (lane & 15);           // chunk-local row
    int sub  = (lane >> 4) & 3;
    const ush* tp = T + (size_t)arow * TLD + sub * 8;
    const ush* ap = act + (size_t)(n0 + arow) * 128 + sub * 8;

    int ks0 = wave * (KSTEPS / 8);

    // prefetch k-step ks0
    v8s a_c = (ks0 < KK * 4) ? *(const v8s*)(tp + ks0 * 32)
                             : *(const v8s*)(ap + (ks0 - KK * 4) * 32);
    v8s b_c[8];
#pragma unroll
    for (int nt = 0; nt < 8; nt++)
        b_c[nt] = *(const v8s*)(Wh + ((size_t)(ks0 * 8 + nt) * 64 + lane) * 8);

    for (int i = 0; i < KSTEPS / 8; i++) {
        int ksn = ks0 + ((i + 1 < KSTEPS / 8) ? i + 1 : i);
        v8s a_n = (ksn < KK * 4) ? *(const v8s*)(tp + ksn * 32)
                                 : *(const v8s*)(ap + (ksn - KK * 4) * 32);
        v8s b_n[8];
#pragma unroll
        for (int nt = 0; nt < 8; nt++)
            b_n[nt] = *(const v8s*)(Wh + ((size_t)(ksn * 8 + nt) * 64 + lane) * 8);
#pragma unroll
        for (int nt = 0; nt < 8; nt++)
            acc[nt] = __builtin_amdgcn_mfma_f32_16x16x32_bf16(a_c, b_c[nt], acc[nt], 0, 0, 0);
        a_c = a_n;
#pragma unroll
        for (int nt = 0; nt < 8; nt++) b_c[nt] = b_n[nt];
    }

    // cross-wave reduce + epilogue, two 64-column passes
    int r  = threadIdx.x >> 5;                 // output row in m-tile 0..15
    int cl = (threadIdx.x & 31) * 2;           // col pair within 64-col pass
    int row = n0 + mtr * 16 + r;
#pragma unroll
    for (int p = 0; p < 2; p++) {
        __syncthreads();
#pragma unroll
        for (int q = 0; q < 16; q++) S[threadIdx.x][q] = acc[p * 4 + (q >> 2)][q & 3];
        __syncthreads();
        float v[2];
#pragma unroll
        for (int h = 0; h < 2; h++) {
            int c = p * 64 + cl + h;               // global output column
            int ln  = (c & 15) + 16 * (r >> 2);    // source lane of C-frag
            int idx = (((c & 63) >> 4) << 2) + (r & 3);
            float s = 0.f;
#pragma unroll
            for (int w = 0; w < 8; w++) s += S[w * 64 + ln][idx];
            s += bias[c];
            if (relu) s = fmaxf(s, 0.f);
            v[h] = s;
        }
        int c0 = p * 64 + cl;
        if (actout) {
            *(unsigned*)(actout + (size_t)row * 128 + c0) = pack2bf(v[0], v[1]);
        } else {
            float2 f2; f2.x = v[0]; f2.y = v[1];
            *(float2*)(fout + (size_t)row * 128 + c0) = f2;
        }
    }
}

// ---------------------------------------------------------------------------
extern "C" void kernel_launch(void* const* d_in, const int* in_sizes, int n_in,
                              void* d_out, int out_size, void* d_ws, size_t ws_size,
                              hipStream_t stream) {
    const float* x   = (const float*)d_in[0];
    const void*  eix = d_in[1];
    const float* ea  = (const float*)d_in[2];
    const float* Wp1 = (const float*)d_in[3];
    const float* bp1 = (const float*)d_in[4];
    const float* Wp2 = (const float*)d_in[5];
    const float* bp2 = (const float*)d_in[6];
    const float* W[3]  = {(const float*)d_in[7],  (const float*)d_in[10], (const float*)d_in[13]};
    const float* Wr[3] = {(const float*)d_in[8],  (const float*)d_in[11], (const float*)d_in[14]};
    const float* b[3]  = {(const float*)d_in[9],  (const float*)d_in[12], (const float*)d_in[15]};
    float* out = (float*)d_out;

    char* ws = (char*)d_ws;
    size_t off = 0;
    auto walloc = [&](size_t bytes) -> void* {
        void* p = ws + off;
        off = (off + bytes + 255) & ~(size_t)255;
        return p;
    };
    int*    flag    = (int*)   walloc(sizeof(int));
    int*    e32     = (int*)   walloc(sizeof(int) * 2 * E_EDGES);
    float4* fb      = (float4*)walloc(sizeof(float4) * (size_t)E_EDGES);
    int*    srcp    = (int*)   walloc(sizeof(int) * E_EDGES);
    int*    eperm   = (int*)   walloc(sizeof(int) * E_EDGES);
    float*  w32p    = (float*) walloc(sizeof(float) * (size_t)E_EDGES * WLD);
    int*    histcur = (int*)   walloc(sizeof(int) * (size_t)N_NODES * 2);
    int*    rowptr  = (int*)   walloc(sizeof(int) * (N_NODES + 1));
    ush*    xb      = (ush*)   walloc(sizeof(ush) * (size_t)N_NODES * 128);
    ush*    a1      = (ush*)   walloc(sizeof(ush) * (size_t)N_NODES * 128);
    ush*    a2      = (ush*)   walloc(sizeof(ush) * (size_t)N_NODES * 128);
    short*  Wh3     = (short*) walloc(sizeof(short) * (size_t)3 * NB * 128 * 128);

    // Runtime chunk-size fallback: T chunk must fit in the remaining ws.
    // 20000 % chunk_n == 0 and chunk_n % 16 == 0 for all candidates.
    int chunk_n = 10000;
    {
        const int cand[3] = {10000, 4000, 2000};
        for (int i = 0; i < 3; i++) {
            size_t need = (size_t)cand[i] * TLD * sizeof(ush);
            chunk_n = cand[i];
            if (off + need <= ws_size) break;
        }
    }
    ush* T = (ush*)walloc((size_t)chunk_n * TLD * sizeof(ush));

    int* srcv = e32;
    int* dstv = e32 + E_EDGES;
    int* hist   = histcur;
    int* cursor = histcur + N_NODES;

    detect_kernel<<<1, 1024, 0, stream>>>((const unsigned int*)eix, flag);
    decode_edges<<<(2 * E_EDGES + 255) / 256, 256, 0, stream>>>(eix, flag, e32, 2 * E_EDGES);
    edge_basis<<<(E_EDGES + 255) / 256, 256, 0, stream>>>(ea, Wp1, bp1, Wp2, bp2, fb);

    // CSR binned by dst; built once, reused across 3 layers
    zero_int<<<(N_NODES * 2 + 255) / 256, 256, 0, stream>>>(histcur, N_NODES * 2);
    hist_kernel<<<(E_EDGES + 255) / 256, 256, 0, stream>>>(dstv, hist);
    scan_kernel<<<1, 256, 0, stream>>>(hist, rowptr, N_NODES);
    perm_kernel<<<(E_EDGES + 255) / 256, 256, 0, stream>>>(dstv, rowptr, cursor, eperm);
    pack_w27<<<(E_EDGES + 255) / 256, 256, 0, stream>>>(eperm, srcv, fb, srcp, w32p);

    packW3_kernel<<<(3 * NB * 4 * 8 * 64 + 255) / 256, 256, 0, stream>>>(
        W[0], Wr[0], W[1], Wr[1], W[2], Wr[2], Wh3);
    conv_xb<<<(N_NODES * CIN / 4 + 255) / 256, 256, 0, stream>>>(x, xb);

    const ush* actin = xb;
    for (int l = 0; l < 3; l++) {
        const short* Wh = Wh3 + (size_t)l * NB * 128 * 128;
        ush* actout = (l == 0) ? a1 : (l == 1) ? a2 : nullptr;
        for (int n0 = 0; n0 < N_NODES; n0 += chunk_n) {
            int cn = (n0 + chunk_n <= N_NODES) ? chunk_n : (N_NODES - n0);
            int nmt = cn / 16;
            accumT_kernel<<<cn, 256, 0, stream>>>(actin, rowptr, srcp, w32p, T, n0);
            gemm2_kernel<<<nmt, 512, 0, stream>>>(
                T, actin, Wh, b[l], actout, (l == 2) ? out : nullptr,
                n0, (l < 2) ? 1 : 0);
        }
        if (l == 0) actin = a1; else if (l == 1) actin = a2;
    }
}

// Round 5
// 715.936 us; speedup vs baseline: 1.1713x; 1.0548x over previous
//
#include <hip/hip_runtime.h>
#include <hip/hip_bf16.h>
#include <hip/hip_fp16.h>

#define N_NODES 20000
#define E_EDGES 320000
#define CIN 128
#define HDIM 128
#define EDGE_DIM 16
#define SDIM 3
#define KS 3
#define KK 27           // 3^3 kernel weight matrices
#define NB 28           // 27 spline blocks + 1 root-weight block
#define KSTEPS 112      // NB*128/32 k-steps of the fused GEMM
#define TLD (KK * 128)  // node-major T leading dim = 3456 shorts (root not stored)
#define WLD 32          // padded per-edge spline-weight stride (fp16 elements)
#define MLP_HID 6

typedef __attribute__((ext_vector_type(8))) short v8s;   // 8 bf16 (4 VGPRs)
typedef __attribute__((ext_vector_type(4))) float v4f;   // MFMA accumulator
typedef unsigned short ush;

static __device__ __forceinline__ short f2bf(float v) {
    unsigned u = __float_as_uint(v);
    unsigned r = (u + 0x7fffu + ((u >> 16) & 1u)) >> 16;   // RTNE
    return (short)r;
}
static __device__ __forceinline__ float bf2f_lo(unsigned u) {   // low short
    return __uint_as_float(u << 16);
}
static __device__ __forceinline__ float bf2f_hi(unsigned u) {   // high short
    return __uint_as_float(u & 0xffff0000u);
}
static __device__ __forceinline__ unsigned pack2bf(float a, float b) {
    return ((unsigned)(ush)f2bf(a)) | (((unsigned)(ush)f2bf(b)) << 16);
}
static __device__ __forceinline__ unsigned short f2h(float f) {
    __half h = __float2half(f);
    return __half_as_ushort(h);
}
static __device__ __forceinline__ float h2f(unsigned u) {
    __half_raw r; r.x = (unsigned short)(u & 0xffffu);
    return __half2float(__half(r));
}

// ---------------------------------------------------------------------------
// edge_index dtype detect + decode (int64 vs int32 storage)
// ---------------------------------------------------------------------------
__global__ void detect_kernel(const unsigned int* __restrict__ e, int* __restrict__ flag) {
    __shared__ int s_nz;
    if (threadIdx.x == 0) s_nz = 0;
    __syncthreads();
    unsigned int v = e[threadIdx.x * 2 + 1];
    if (v != 0) atomicAdd(&s_nz, 1);
    __syncthreads();
    if (threadIdx.x == 0) *flag = (s_nz > 0) ? 1 : 0;
}

__global__ void decode_edges(const void* __restrict__ eraw, const int* __restrict__ flag,
                             int* __restrict__ e32, int n) {
    int i = blockIdx.x * blockDim.x + threadIdx.x;
    if (i >= n) return;
    if (*flag) e32[i] = ((const int*)eraw)[i];
    else       e32[i] = (int)(((const long long*)eraw)[i]);
}

// ---------------------------------------------------------------------------
// Edge MLP (16->6 relu ->3 sigmoid) -> (frac[3], lo[3]) per edge, packed 16 B.
// ---------------------------------------------------------------------------
__global__ void edge_basis(const float* __restrict__ ea,
                           const float* __restrict__ Wp1, const float* __restrict__ bp1,
                           const float* __restrict__ Wp2, const float* __restrict__ bp2,
                           float4* __restrict__ fb) {
    __shared__ float sW1[EDGE_DIM * MLP_HID];
    __shared__ float sb1[MLP_HID];
    __shared__ float sW2[MLP_HID * SDIM];
    __shared__ float sb2[SDIM];
    int t = threadIdx.x;
    if (t < EDGE_DIM * MLP_HID) sW1[t] = Wp1[t];
    if (t < MLP_HID)            sb1[t] = bp1[t];
    if (t < MLP_HID * SDIM)     sW2[t] = Wp2[t];
    if (t < SDIM)               sb2[t] = bp2[t];
    __syncthreads();
    int e = blockIdx.x * blockDim.x + t;
    if (e >= E_EDGES) return;

    float a[EDGE_DIM];
#pragma unroll
    for (int i = 0; i < EDGE_DIM; i++) a[i] = ea[(long)e * EDGE_DIM + i];

    float hid[MLP_HID];
#pragma unroll
    for (int j = 0; j < MLP_HID; j++) {
        float s = sb1[j];
#pragma unroll
        for (int i = 0; i < EDGE_DIM; i++) s += a[i] * sW1[i * MLP_HID + j];
        hid[j] = fmaxf(s, 0.f);
    }

    float fr[SDIM];
    unsigned lp = 0;
#pragma unroll
    for (int d = 0; d < SDIM; d++) {
        float s = sb2[d];
#pragma unroll
        for (int j = 0; j < MLP_HID; j++) s += hid[j] * sW2[j * SDIM + d];
        float u = 1.f / (1.f + expf(-s));
        float v = u * (float)(KS - 1);
        float l = floorf(v);
        l = fminf(fmaxf(l, 0.f), (float)(KS - 2));
        fr[d] = v - l;
        lp |= ((unsigned)(int)l) << (8 * d);
    }
    float4 o;
    o.x = fr[0]; o.y = fr[1]; o.z = fr[2]; o.w = __uint_as_float(lp);
    fb[e] = o;
}

// ---------------------------------------------------------------------------
// CSR build binned by dst — built once, reused for 3 layers
// ---------------------------------------------------------------------------
__global__ void zero_int(int* __restrict__ p, int n) {
    int i = blockIdx.x * blockDim.x + threadIdx.x;
    if (i < n) p[i] = 0;
}

__global__ void hist_kernel(const int* __restrict__ dst, int* __restrict__ hist) {
    int e = blockIdx.x * blockDim.x + threadIdx.x;
    if (e >= E_EDGES) return;
    atomicAdd(&hist[dst[e]], 1);
}

__global__ void scan_kernel(const int* __restrict__ hist, int* __restrict__ rowptr, int B) {
    __shared__ int part[256];
    int t = threadIdx.x;
    const int per = (B + 255) / 256;
    int base = t * per;
    int s = 0;
    for (int i = 0; i < per; i++) {
        int idx = base + i;
        if (idx < B) s += hist[idx];
    }
    part[t] = s;
    __syncthreads();
    for (int off = 1; off < 256; off <<= 1) {
        int v = (t >= off) ? part[t - off] : 0;
        __syncthreads();
        part[t] += v;
        __syncthreads();
    }
    int run = (t == 0) ? 0 : part[t - 1];
    for (int i = 0; i < per; i++) {
        int idx = base + i;
        if (idx < B) { rowptr[idx] = run; run += hist[idx]; }
    }
    if (t == 255) rowptr[B] = run;
}

__global__ void perm_kernel(const int* __restrict__ dst,
                            const int* __restrict__ rowptr, int* __restrict__ cursor,
                            int* __restrict__ eperm) {
    int e = blockIdx.x * blockDim.x + threadIdx.x;
    if (e >= E_EDGES) return;
    int bin = dst[e];
    int pos = rowptr[bin] + atomicAdd(&cursor[bin], 1);
    eperm[pos] = e;
}

// ---------------------------------------------------------------------------
// Pack per-edge metadata into CSR order: src index + DENSE spline weights as
// fp16, padded to 32 halves (64 B): wave w of accumT reads halves [8w, 8w+8)
// as one uint4. Halves 27..31 are zero. fp16 (11-bit mantissa) keeps the
// weight quantization error well below the bf16 activation error.
// ---------------------------------------------------------------------------
__global__ void pack_wh(const int* __restrict__ eperm, const int* __restrict__ src,
                        const float4* __restrict__ fb,
                        int* __restrict__ srcp, ush* __restrict__ w32h) {
    int j = blockIdx.x * blockDim.x + threadIdx.x;
    if (j >= E_EDGES) return;
    int e = eperm[j];
    srcp[j] = src[e];
    float4 f = fb[e];
    unsigned lp = __float_as_uint(f.w);
    float fr[3] = {f.x, f.y, f.z};
    float t[3][3];
#pragma unroll
    for (int d = 0; d < 3; d++) {
        int lo = (lp >> (8 * d)) & 255;
        float fd = fr[d];
#pragma unroll
        for (int q = 0; q < 3; q++)
            t[d][q] = (q == lo) ? (1.f - fd) : (q == lo + 1) ? fd : 0.f;
    }
    float out[WLD];
#pragma unroll
    for (int q = 0; q < WLD; q++) out[q] = 0.f;
#pragma unroll
    for (int k2 = 0; k2 < 3; k2++)
#pragma unroll
        for (int k1 = 0; k1 < 3; k1++)
#pragma unroll
            for (int k0 = 0; k0 < 3; k0++)
                out[k2 * 9 + k1 * 3 + k0] = t[0][k0] * t[1][k1] * t[2][k2];
    ush h[WLD];
#pragma unroll
    for (int q = 0; q < WLD; q++) h[q] = f2h(out[q]);
    ush* op = w32h + (size_t)j * WLD;
#pragma unroll
    for (int q = 0; q < WLD / 8; q++)
        *(uint4*)(op + 8 * q) = *(uint4*)(h + 8 * q);
}

// ---------------------------------------------------------------------------
// Pack [W (27 blocks) | Wr] of ALL 3 LAYERS -> bf16 MFMA B-fragment layout.
// Layout [layer][flat_ks=kb*4+ks][nt][64][8] — one fused K=3584 B panel.
// ---------------------------------------------------------------------------
__global__ void packW3_kernel(const float* __restrict__ W0, const float* __restrict__ Wr0,
                              const float* __restrict__ W1, const float* __restrict__ Wr1,
                              const float* __restrict__ W2, const float* __restrict__ Wr2,
                              short* __restrict__ hi) {
    int gid = blockIdx.x * blockDim.x + threadIdx.x;
    if (gid >= 3 * NB * 4 * 8 * 64) return;
    int lane = gid & 63;
    int nt = (gid >> 6) & 7;
    int ks = (gid >> 9) & 3;
    int kb2 = gid >> 11;           // 0..83
    int layer = kb2 / NB;
    int kb = kb2 - layer * NB;
    const float* W  = (layer == 0) ? W0  : (layer == 1) ? W1  : W2;
    const float* Wr = (layer == 0) ? Wr0 : (layer == 1) ? Wr1 : Wr2;
    int i0 = ks * 32 + ((lane >> 4) & 3) * 8;
    int o = nt * 16 + (lane & 15);
    const float* src = (kb < KK) ? (W + (long)kb * 16384 + (long)i0 * 128 + o)
                                 : (Wr + (long)i0 * 128 + o);
    long off = ((long)(((size_t)layer * NB + kb) * 4 + ks) * 8 + nt) * 64 * 8
             + (long)lane * 8;
#pragma unroll
    for (int j = 0; j < 8; j++) {
        float v = src[(long)j * 128];
        hi[off + j] = f2bf(v);
    }
}

// ---------------------------------------------------------------------------
// x (fp32) -> xb (bf16 row-major) once; later layers' activations are written
// bf16 row-major by the GEMM epilogue directly.
// ---------------------------------------------------------------------------
__global__ void conv_xb(const float* __restrict__ x, ush* __restrict__ xb) {
    int i = blockIdx.x * blockDim.x + threadIdx.x;
    if (i >= N_NODES * CIN / 4) return;
    float4 v = ((const float4*)x)[i];
    uint2 d;
    d.x = pack2bf(v.x, v.y);
    d.y = pack2bf(v.z, v.w);
    ((uint2*)xb)[i] = d;
}

// ---------------------------------------------------------------------------
// accumT v4: one block (4 waves) per dst node; wave w owns k in [8w, 8w+8).
// Lane owns channels (2l, 2l+1). Per edge per wave: 1x 4B act load +
// 1x uint4 fp16-weight load. Software pipeline: act/w prefetched at DEPTH 2,
// srcp at DEPTH 4 — the srcp->act dependent pair never sits on the critical
// path. T written node-major, full 256 B coalesced lines per (n,k).
// ---------------------------------------------------------------------------
__global__ __launch_bounds__(256) void accumT_kernel(
    const ush* __restrict__ act, const int* __restrict__ rowptr,
    const int* __restrict__ srcp, const ush* __restrict__ w32h,
    ush* __restrict__ T, int n0)
{
    int lane = threadIdx.x & 63;
    int wave = threadIdx.x >> 6;         // k-split 0..3
    int n = n0 + blockIdx.x;
    int jb = rowptr[n], je = rowptr[n + 1];

    float acc[8][2];
#pragma unroll
    for (int k = 0; k < 8; k++) { acc[k][0] = 0.f; acc[k][1] = 0.f; }

    const ush* actl = act + lane * 2;          // channel-pair base
    const ush* wl   = w32h + wave * 8;         // wave's 16B fp16 window

    if (jb < je) {
        int last = je - 1;
        int j1 = (jb + 1 > last) ? last : jb + 1;
        int j2 = (jb + 2 > last) ? last : jb + 2;
        int j3 = (jb + 3 > last) ? last : jb + 3;
        int sA = srcp[jb], sB = srcp[j1];
        int sP = srcp[j2], sQ = srcp[j3];
        unsigned xA = *(const unsigned*)(actl + (size_t)sA * 128);
        unsigned xB = *(const unsigned*)(actl + (size_t)sB * 128);
        uint4 wA = *(const uint4*)(wl + (size_t)jb * WLD);
        uint4 wB = *(const uint4*)(wl + (size_t)j1 * WLD);

        for (int j = jb; j < je; j++) {
            int jn2 = (j + 2 > last) ? last : j + 2;
            int jn4 = (j + 4 > last) ? last : j + 4;
            // prefetches (depth 2 for act/w, depth 4 for srcp)
            unsigned xn = *(const unsigned*)(actl + (size_t)sP * 128);
            uint4 wn = *(const uint4*)(wl + (size_t)jn2 * WLD);
            int sR = srcp[jn4];
            // compute edge j
            float x0 = bf2f_lo(xA);
            float x1 = bf2f_hi(xA);
            float w[8] = {h2f(wA.x), h2f(wA.x >> 16), h2f(wA.y), h2f(wA.y >> 16),
                          h2f(wA.z), h2f(wA.z >> 16), h2f(wA.w), h2f(wA.w >> 16)};
#pragma unroll
            for (int k = 0; k < 8; k++) {
                acc[k][0] += w[k] * x0;
                acc[k][1] += w[k] * x1;
            }
            xA = xB; wA = wB; xB = xn; wB = wn; sP = sQ; sQ = sR;
        }
    }

    ush* tp = T + (size_t)(n - n0) * TLD + lane * 2;
    int kb = wave * 8;
#pragma unroll
    for (int k = 0; k < 8; k++) {
        int kk = kb + k;
        if (kk < KK)
            *(unsigned*)(tp + (size_t)kk * 128) = pack2bf(acc[k][0], acc[k][1]);
    }
}

// ---------------------------------------------------------------------------
// gemm2 v4: out[n,o] = [T_row(3456) | act_row(128)] . Wall(3584x128) + bias
// 512 threads / 8 waves, TWO m-tiles (32 rows) per block -> B-panel L2
// traffic halved vs one m-tile, and 16 MFMAs per k-step cover the B-load
// latency at prefetch depth 1. Wave w owns 14 k-steps; cross-wave reduce
// through LDS in four 64-col passes (LDS 34.8 KB).
// ---------------------------------------------------------------------------
__global__ __launch_bounds__(512) void gemm2_kernel(
    const ush* __restrict__ T, const ush* __restrict__ act,
    const short* __restrict__ Wh, const float* __restrict__ bias,
    ush* __restrict__ actout, float* __restrict__ fout,
    int n0, int nmt, int relu)
{
    __shared__ float S[512][17];
    int lane = threadIdx.x & 63;
    int wave = threadIdx.x >> 6;
    int mtr0 = blockIdx.x * 2;
    int mv = (nmt - mtr0 >= 2) ? 2 : 1;

    v4f acc[2][8];
#pragma unroll
    for (int m = 0; m < 2; m++)
#pragma unroll
        for (int nt = 0; nt < 8; nt++) acc[m][nt] = (v4f){0.f, 0.f, 0.f, 0.f};

    int r15 = lane & 15;
    int sub = (lane >> 4) & 3;
    int arow0 = mtr0 * 16 + r15;
    int arow1 = (mv > 1) ? arow0 + 16 : arow0;       // clamped duplicate if tail
    const ush* tp0 = T + (size_t)arow0 * TLD + sub * 8;
    const ush* tp1 = T + (size_t)arow1 * TLD + sub * 8;
    const ush* ap0 = act + (size_t)(n0 + arow0) * 128 + sub * 8;
    const ush* ap1 = act + (size_t)(n0 + arow1) * 128 + sub * 8;

    int ks0 = wave * (KSTEPS / 8);

    v8s a0c = (ks0 < KK * 4) ? *(const v8s*)(tp0 + ks0 * 32)
                             : *(const v8s*)(ap0 + (ks0 - KK * 4) * 32);
    v8s a1c = (ks0 < KK * 4) ? *(const v8s*)(tp1 + ks0 * 32)
                             : *(const v8s*)(ap1 + (ks0 - KK * 4) * 32);
    v8s b_c[8];
#pragma unroll
    for (int nt = 0; nt < 8; nt++)
        b_c[nt] = *(const v8s*)(Wh + ((size_t)(ks0 * 8 + nt) * 64 + lane) * 8);

    for (int i = 0; i < KSTEPS / 8; i++) {
        int ksn = ks0 + ((i + 1 < KSTEPS / 8) ? i + 1 : i);
        v8s a0n = (ksn < KK * 4) ? *(const v8s*)(tp0 + ksn * 32)
                                 : *(const v8s*)(ap0 + (ksn - KK * 4) * 32);
        v8s a1n = (ksn < KK * 4) ? *(const v8s*)(tp1 + ksn * 32)
                                 : *(const v8s*)(ap1 + (ksn - KK * 4) * 32);
        v8s b_n[8];
#pragma unroll
        for (int nt = 0; nt < 8; nt++)
            b_n[nt] = *(const v8s*)(Wh + ((size_t)(ksn * 8 + nt) * 64 + lane) * 8);
#pragma unroll
        for (int nt = 0; nt < 8; nt++)
            acc[0][nt] = __builtin_amdgcn_mfma_f32_16x16x32_bf16(a0c, b_c[nt], acc[0][nt], 0, 0, 0);
#pragma unroll
        for (int nt = 0; nt < 8; nt++)
            acc[1][nt] = __builtin_amdgcn_mfma_f32_16x16x32_bf16(a1c, b_c[nt], acc[1][nt], 0, 0, 0);
        a0c = a0n; a1c = a1n;
#pragma unroll
        for (int nt = 0; nt < 8; nt++) b_c[nt] = b_n[nt];
    }

    // cross-wave reduce + epilogue: four passes (2 m-tiles x 2 column halves)
    int r  = threadIdx.x >> 5;                 // output row in m-tile 0..15
    int cl = (threadIdx.x & 31) * 2;           // col pair within 64-col pass
#pragma unroll
    for (int m = 0; m < 2; m++) {
        int row = n0 + (mtr0 + m) * 16 + r;
#pragma unroll
        for (int p = 0; p < 2; p++) {
            __syncthreads();
#pragma unroll
            for (int q = 0; q < 16; q++)
                S[threadIdx.x][q] = acc[m][p * 4 + (q >> 2)][q & 3];
            __syncthreads();
            if (m < mv) {
                float v[2];
#pragma unroll
                for (int h = 0; h < 2; h++) {
                    int c = p * 64 + cl + h;               // global output column
                    int ln  = (c & 15) + 16 * (r >> 2);    // source lane of C-frag
                    int idx = (((c & 63) >> 4) << 2) + (r & 3);
                    float s = 0.f;
#pragma unroll
                    for (int w = 0; w < 8; w++) s += S[w * 64 + ln][idx];
                    s += bias[c];
                    if (relu) s = fmaxf(s, 0.f);
                    v[h] = s;
                }
                int c0 = p * 64 + cl;
                if (actout) {
                    *(unsigned*)(actout + (size_t)row * 128 + c0) = pack2bf(v[0], v[1]);
                } else {
                    float2 f2; f2.x = v[0]; f2.y = v[1];
                    *(float2*)(fout + (size_t)row * 128 + c0) = f2;
                }
            }
        }
    }
}

// ---------------------------------------------------------------------------
extern "C" void kernel_launch(void* const* d_in, const int* in_sizes, int n_in,
                              void* d_out, int out_size, void* d_ws, size_t ws_size,
                              hipStream_t stream) {
    const float* x   = (const float*)d_in[0];
    const void*  eix = d_in[1];
    const float* ea  = (const float*)d_in[2];
    const float* Wp1 = (const float*)d_in[3];
    const float* bp1 = (const float*)d_in[4];
    const float* Wp2 = (const float*)d_in[5];
    const float* bp2 = (const float*)d_in[6];
    const float* W[3]  = {(const float*)d_in[7],  (const float*)d_in[10], (const float*)d_in[13]};
    const float* Wr[3] = {(const float*)d_in[8],  (const float*)d_in[11], (const float*)d_in[14]};
    const float* b[3]  = {(const float*)d_in[9],  (const float*)d_in[12], (const float*)d_in[15]};
    float* out = (float*)d_out;

    char* ws = (char*)d_ws;
    size_t off = 0;
    auto walloc = [&](size_t bytes) -> void* {
        void* p = ws + off;
        off = (off + bytes + 255) & ~(size_t)255;
        return p;
    };
    int*    flag    = (int*)   walloc(sizeof(int));
    int*    e32     = (int*)   walloc(sizeof(int) * 2 * E_EDGES);
    float4* fb      = (float4*)walloc(sizeof(float4) * (size_t)E_EDGES);
    int*    srcp    = (int*)   walloc(sizeof(int) * E_EDGES);
    int*    eperm   = (int*)   walloc(sizeof(int) * E_EDGES);
    ush*    w32h    = (ush*)   walloc(sizeof(ush) * (size_t)E_EDGES * WLD);
    int*    histcur = (int*)   walloc(sizeof(int) * (size_t)N_NODES * 2);
    int*    rowptr  = (int*)   walloc(sizeof(int) * (N_NODES + 1));
    ush*    xb      = (ush*)   walloc(sizeof(ush) * (size_t)N_NODES * 128);
    ush*    a1      = (ush*)   walloc(sizeof(ush) * (size_t)N_NODES * 128);
    ush*    a2      = (ush*)   walloc(sizeof(ush) * (size_t)N_NODES * 128);
    short*  Wh3     = (short*) walloc(sizeof(short) * (size_t)3 * NB * 128 * 128);

    // Runtime chunk-size fallback: T chunk must fit in the remaining ws.
    // 20000 % chunk_n == 0 and chunk_n % 32 == 0 for all candidates.
    int chunk_n = 10000;
    {
        const int cand[3] = {10000, 4000, 2000};
        for (int i = 0; i < 3; i++) {
            size_t need = (size_t)cand[i] * TLD * sizeof(ush);
            chunk_n = cand[i];
            if (off + need <= ws_size) break;
        }
    }
    ush* T = (ush*)walloc((size_t)chunk_n * TLD * sizeof(ush));

    int* srcv = e32;
    int* dstv = e32 + E_EDGES;
    int* hist   = histcur;
    int* cursor = histcur + N_NODES;

    detect_kernel<<<1, 1024, 0, stream>>>((const unsigned int*)eix, flag);
    decode_edges<<<(2 * E_EDGES + 255) / 256, 256, 0, stream>>>(eix, flag, e32, 2 * E_EDGES);
    edge_basis<<<(E_EDGES + 255) / 256, 256, 0, stream>>>(ea, Wp1, bp1, Wp2, bp2, fb);

    // CSR binned by dst; built once, reused across 3 layers
    zero_int<<<(N_NODES * 2 + 255) / 256, 256, 0, stream>>>(histcur, N_NODES * 2);
    hist_kernel<<<(E_EDGES + 255) / 256, 256, 0, stream>>>(dstv, hist);
    scan_kernel<<<1, 256, 0, stream>>>(hist, rowptr, N_NODES);
    perm_kernel<<<(E_EDGES + 255) / 256, 256, 0, stream>>>(dstv, rowptr, cursor, eperm);
    pack_wh<<<(E_EDGES + 255) / 256, 256, 0, stream>>>(eperm, srcv, fb, srcp, w32h);

    packW3_kernel<<<(3 * NB * 4 * 8 * 64 + 255) / 256, 256, 0, stream>>>(
        W[0], Wr[0], W[1], Wr[1], W[2], Wr[2], Wh3);
    conv_xb<<<(N_NODES * CIN / 4 + 255) / 256, 256, 0, stream>>>(x, xb);

    const ush* actin = xb;
    for (int l = 0; l < 3; l++) {
        const short* Wh = Wh3 + (size_t)l * NB * 128 * 128;
        ush* actout = (l == 0) ? a1 : (l == 1) ? a2 : nullptr;
        for (int n0 = 0; n0 < N_NODES; n0 += chunk_n) {
            int cn = (n0 + chunk_n <= N_NODES) ? chunk_n : (N_NODES - n0);
            int nmt = cn / 16;
            accumT_kernel<<<cn, 256, 0, stream>>>(actin, rowptr, srcp, w32h, T, n0);
            gemm2_kernel<<<(nmt + 1) / 2, 512, 0, stream>>>(
                T, actin, Wh, b[l], actout, (l == 2) ? out : nullptr,
                n0, nmt, (l < 2) ? 1 : 0);
        }
        if (l == 0) actin = a1; else if (l == 1) actin = a2;
    }
}

// Round 6
// 620.037 us; speedup vs baseline: 1.3524x; 1.1547x over previous
//
#include <hip/hip_runtime.h>
#include <hip/hip_bf16.h>
#include <hip/hip_fp16.h>

#define N_NODES 20000
#define E_EDGES 320000
#define CIN 128
#define HDIM 128
#define EDGE_DIM 16
#define SDIM 3
#define KS 3
#define KK 27           // 3^3 kernel weight matrices
#define NB 28           // 27 spline blocks + 1 root-weight block
#define KSTEPS 112      // NB*128/32 k-steps of the fused GEMM
#define TLD (KK * 128)  // node-major T leading dim = 3456 shorts (root not stored)
#define WLD 28          // per-edge fp32 spline-weight stride (floats, 7 x float4)
#define MLP_HID 6

typedef __attribute__((ext_vector_type(8))) short v8s;   // 8 bf16 (4 VGPRs)
typedef __attribute__((ext_vector_type(4))) float v4f;   // MFMA accumulator
typedef unsigned short ush;

static __device__ __forceinline__ short f2bf(float v) {
    unsigned u = __float_as_uint(v);
    unsigned r = (u + 0x7fffu + ((u >> 16) & 1u)) >> 16;   // RTNE
    return (short)r;
}
static __device__ __forceinline__ float bf2f_lo(unsigned u) {   // low short
    return __uint_as_float(u << 16);
}
static __device__ __forceinline__ float bf2f_hi(unsigned u) {   // high short
    return __uint_as_float(u & 0xffff0000u);
}
static __device__ __forceinline__ unsigned pack2bf(float a, float b) {
    return ((unsigned)(ush)f2bf(a)) | (((unsigned)(ush)f2bf(b)) << 16);
}

// ---------------------------------------------------------------------------
// edge_index dtype detect + decode (int64 vs int32 storage)
// ---------------------------------------------------------------------------
__global__ void detect_kernel(const unsigned int* __restrict__ e, int* __restrict__ flag) {
    __shared__ int s_nz;
    if (threadIdx.x == 0) s_nz = 0;
    __syncthreads();
    unsigned int v = e[threadIdx.x * 2 + 1];
    if (v != 0) atomicAdd(&s_nz, 1);
    __syncthreads();
    if (threadIdx.x == 0) *flag = (s_nz > 0) ? 1 : 0;
}

__global__ void decode_edges(const void* __restrict__ eraw, const int* __restrict__ flag,
                             int* __restrict__ e32, int n) {
    int i = blockIdx.x * blockDim.x + threadIdx.x;
    if (i >= n) return;
    if (*flag) e32[i] = ((const int*)eraw)[i];
    else       e32[i] = (int)(((const long long*)eraw)[i]);
}

// ---------------------------------------------------------------------------
// Edge MLP (16->6 relu ->3 sigmoid) -> (frac[3], lo[3]) per edge, packed 16 B.
// ---------------------------------------------------------------------------
__global__ void edge_basis(const float* __restrict__ ea,
                           const float* __restrict__ Wp1, const float* __restrict__ bp1,
                           const float* __restrict__ Wp2, const float* __restrict__ bp2,
                           float4* __restrict__ fb) {
    __shared__ float sW1[EDGE_DIM * MLP_HID];
    __shared__ float sb1[MLP_HID];
    __shared__ float sW2[MLP_HID * SDIM];
    __shared__ float sb2[SDIM];
    int t = threadIdx.x;
    if (t < EDGE_DIM * MLP_HID) sW1[t] = Wp1[t];
    if (t < MLP_HID)            sb1[t] = bp1[t];
    if (t < MLP_HID * SDIM)     sW2[t] = Wp2[t];
    if (t < SDIM)               sb2[t] = bp2[t];
    __syncthreads();
    int e = blockIdx.x * blockDim.x + t;
    if (e >= E_EDGES) return;

    float a[EDGE_DIM];
#pragma unroll
    for (int i = 0; i < EDGE_DIM; i++) a[i] = ea[(long)e * EDGE_DIM + i];

    float hid[MLP_HID];
#pragma unroll
    for (int j = 0; j < MLP_HID; j++) {
        float s = sb1[j];
#pragma unroll
        for (int i = 0; i < EDGE_DIM; i++) s += a[i] * sW1[i * MLP_HID + j];
        hid[j] = fmaxf(s, 0.f);
    }

    float fr[SDIM];
    unsigned lp = 0;
#pragma unroll
    for (int d = 0; d < SDIM; d++) {
        float s = sb2[d];
#pragma unroll
        for (int j = 0; j < MLP_HID; j++) s += hid[j] * sW2[j * SDIM + d];
        float u = 1.f / (1.f + expf(-s));
        float v = u * (float)(KS - 1);
        float l = floorf(v);
        l = fminf(fmaxf(l, 0.f), (float)(KS - 2));
        fr[d] = v - l;
        lp |= ((unsigned)(int)l) << (8 * d);
    }
    float4 o;
    o.x = fr[0]; o.y = fr[1]; o.z = fr[2]; o.w = __uint_as_float(lp);
    fb[e] = o;
}

// ---------------------------------------------------------------------------
// CSR build binned by dst — built once, reused for 3 layers
// ---------------------------------------------------------------------------
__global__ void zero_int(int* __restrict__ p, int n) {
    int i = blockIdx.x * blockDim.x + threadIdx.x;
    if (i < n) p[i] = 0;
}

__global__ void hist_kernel(const int* __restrict__ dst, int* __restrict__ hist) {
    int e = blockIdx.x * blockDim.x + threadIdx.x;
    if (e >= E_EDGES) return;
    atomicAdd(&hist[dst[e]], 1);
}

__global__ void scan_kernel(const int* __restrict__ hist, int* __restrict__ rowptr, int B) {
    __shared__ int part[256];
    int t = threadIdx.x;
    const int per = (B + 255) / 256;
    int base = t * per;
    int s = 0;
    for (int i = 0; i < per; i++) {
        int idx = base + i;
        if (idx < B) s += hist[idx];
    }
    part[t] = s;
    __syncthreads();
    for (int off = 1; off < 256; off <<= 1) {
        int v = (t >= off) ? part[t - off] : 0;
        __syncthreads();
        part[t] += v;
        __syncthreads();
    }
    int run = (t == 0) ? 0 : part[t - 1];
    for (int i = 0; i < per; i++) {
        int idx = base + i;
        if (idx < B) { rowptr[idx] = run; run += hist[idx]; }
    }
    if (t == 255) rowptr[B] = run;
}

__global__ void perm_kernel(const int* __restrict__ dst,
                            const int* __restrict__ rowptr, int* __restrict__ cursor,
                            int* __restrict__ eperm) {
    int e = blockIdx.x * blockDim.x + threadIdx.x;
    if (e >= E_EDGES) return;
    int bin = dst[e];
    int pos = rowptr[bin] + atomicAdd(&cursor[bin], 1);
    eperm[pos] = e;
}

// ---------------------------------------------------------------------------
// Pack per-edge metadata into CSR order: src index + DENSE 27 fp32 spline
// weights (stride 28 floats = 7 float4). fp32: zero conversion cost in the
// accumulate loop, and the loads are block-uniform -> scalar (SMEM) pipe.
// ---------------------------------------------------------------------------
__global__ void pack_w27(const int* __restrict__ eperm, const int* __restrict__ src,
                         const float4* __restrict__ fb,
                         int* __restrict__ srcp, float* __restrict__ w28p) {
    int j = blockIdx.x * blockDim.x + threadIdx.x;
    if (j >= E_EDGES) return;
    int e = eperm[j];
    srcp[j] = src[e];
    float4 f = fb[e];
    unsigned lp = __float_as_uint(f.w);
    float fr[3] = {f.x, f.y, f.z};
    float t[3][3];
#pragma unroll
    for (int d = 0; d < 3; d++) {
        int lo = (lp >> (8 * d)) & 255;
        float fd = fr[d];
#pragma unroll
        for (int q = 0; q < 3; q++)
            t[d][q] = (q == lo) ? (1.f - fd) : (q == lo + 1) ? fd : 0.f;
    }
    float out[WLD];
#pragma unroll
    for (int k2 = 0; k2 < 3; k2++)
#pragma unroll
        for (int k1 = 0; k1 < 3; k1++)
#pragma unroll
            for (int k0 = 0; k0 < 3; k0++)
                out[k2 * 9 + k1 * 3 + k0] = t[0][k0] * t[1][k1] * t[2][k2];
    out[27] = 0.f;
    float* op = w28p + (size_t)j * WLD;
#pragma unroll
    for (int q = 0; q < WLD / 4; q++) *(float4*)(op + 4 * q) = *(float4*)(out + 4 * q);
}

// ---------------------------------------------------------------------------
// Pack [W (27 blocks) | Wr] of ALL 3 LAYERS -> bf16 MFMA B-fragment layout.
// Layout [layer][flat_ks=kb*4+ks][nt][64][8] — one fused K=3584 B panel.
// ---------------------------------------------------------------------------
__global__ void packW3_kernel(const float* __restrict__ W0, const float* __restrict__ Wr0,
                              const float* __restrict__ W1, const float* __restrict__ Wr1,
                              const float* __restrict__ W2, const float* __restrict__ Wr2,
                              short* __restrict__ hi) {
    int gid = blockIdx.x * blockDim.x + threadIdx.x;
    if (gid >= 3 * NB * 4 * 8 * 64) return;
    int lane = gid & 63;
    int nt = (gid >> 6) & 7;
    int ks = (gid >> 9) & 3;
    int kb2 = gid >> 11;           // 0..83
    int layer = kb2 / NB;
    int kb = kb2 - layer * NB;
    const float* W  = (layer == 0) ? W0  : (layer == 1) ? W1  : W2;
    const float* Wr = (layer == 0) ? Wr0 : (layer == 1) ? Wr1 : Wr2;
    int i0 = ks * 32 + ((lane >> 4) & 3) * 8;
    int o = nt * 16 + (lane & 15);
    const float* src = (kb < KK) ? (W + (long)kb * 16384 + (long)i0 * 128 + o)
                                 : (Wr + (long)i0 * 128 + o);
    long off = ((long)(((size_t)layer * NB + kb) * 4 + ks) * 8 + nt) * 64 * 8
             + (long)lane * 8;
#pragma unroll
    for (int j = 0; j < 8; j++) {
        float v = src[(long)j * 128];
        hi[off + j] = f2bf(v);
    }
}

// ---------------------------------------------------------------------------
// x (fp32) -> xb (bf16 row-major) once; later layers' activations are written
// bf16 row-major by the GEMM epilogue directly.
// ---------------------------------------------------------------------------
__global__ void conv_xb(const float* __restrict__ x, ush* __restrict__ xb) {
    int i = blockIdx.x * blockDim.x + threadIdx.x;
    if (i >= N_NODES * CIN / 4) return;
    float4 v = ((const float4*)x)[i];
    uint2 d;
    d.x = pack2bf(v.x, v.y);
    d.y = pack2bf(v.z, v.w);
    ((uint2*)xb)[i] = d;
}

// ---------------------------------------------------------------------------
// accumT v5: ONE NODE PER 64-THREAD BLOCK. All per-edge metadata addresses
// (rowptr, srcp, w28p) are block-uniform -> the compiler provably scalarizes
// them onto the SMEM pipe, leaving the VALU for the 54 FMAs/edge. Lane owns
// channels (2l, 2l+1); acc = 54 fp32 regs, static indices.
// Ping-pong unroll-by-2 pipeline (no rotation movs): per slot, act+weights
// are prefetched 2 edges ahead (~2x120cy cover), srcp 4 ahead.
// T written node-major, full 256 B coalesced lines per (n,k).
// ---------------------------------------------------------------------------
__global__ __launch_bounds__(64) void accumT_kernel(
    const ush* __restrict__ act, const int* __restrict__ rowptr,
    const int* __restrict__ srcp, const float* __restrict__ w28p,
    ush* __restrict__ T, int n0)
{
    int lane = threadIdx.x;
    int n = n0 + blockIdx.x;
    int jb = rowptr[n], je = rowptr[n + 1];

    float acc[KK][2];
#pragma unroll
    for (int k = 0; k < KK; k++) { acc[k][0] = 0.f; acc[k][1] = 0.f; }

    const ush* actl = act + lane * 2;                 // channel-pair base
    const float4* w4 = (const float4*)w28p;           // stride 7 per edge

    if (jb < je) {
        int last = je - 1;
        int j1 = (jb + 1 > last) ? last : jb + 1;
        int j2 = (jb + 2 > last) ? last : jb + 2;
        int j3 = (jb + 3 > last) ? last : jb + 3;
        // slot 0 = even edges (jb, jb+2, ...), slot 1 = odd edges
        unsigned x0c = *(const unsigned*)(actl + (size_t)srcp[jb] * 128);
        unsigned x1c = *(const unsigned*)(actl + (size_t)j1 * 0 + (size_t)srcp[j1] * 128);
        float4 w0c[7], w1c[7];
#pragma unroll
        for (int q = 0; q < 7; q++) w0c[q] = w4[(size_t)jb * 7 + q];
#pragma unroll
        for (int q = 0; q < 7; q++) w1c[q] = w4[(size_t)j1 * 7 + q];
        int s0n = srcp[j2];          // src of the edge slot0 prefetches next
        int s1n = srcp[j3];

        for (int j = jb; j < je; j += 2) {
            // ---- compute slot 0 (edge j) ----
            {
                float x0 = bf2f_lo(x0c), x1 = bf2f_hi(x0c);
                float w[28];
#pragma unroll
                for (int q = 0; q < 7; q++) *(float4*)(w + 4 * q) = w0c[q];
#pragma unroll
                for (int k = 0; k < KK; k++) {
                    acc[k][0] += w[k] * x0;
                    acc[k][1] += w[k] * x1;
                }
            }
            // ---- prefetch slot 0 <- edge j+2 ----
            {
                int jn = (j + 2 > last) ? last : j + 2;
                x0c = *(const unsigned*)(actl + (size_t)s0n * 128);
#pragma unroll
                for (int q = 0; q < 7; q++) w0c[q] = w4[(size_t)jn * 7 + q];
                int jf = (j + 4 > last) ? last : j + 4;
                s0n = srcp[jf];
            }
            // ---- compute slot 1 (edge j+1) + prefetch <- edge j+3 ----
            if (j + 1 < je) {
                {
                    float x0 = bf2f_lo(x1c), x1 = bf2f_hi(x1c);
                    float w[28];
#pragma unroll
                    for (int q = 0; q < 7; q++) *(float4*)(w + 4 * q) = w1c[q];
#pragma unroll
                    for (int k = 0; k < KK; k++) {
                        acc[k][0] += w[k] * x0;
                        acc[k][1] += w[k] * x1;
                    }
                }
                int jn = (j + 3 > last) ? last : j + 3;
                x1c = *(const unsigned*)(actl + (size_t)s1n * 128);
#pragma unroll
                for (int q = 0; q < 7; q++) w1c[q] = w4[(size_t)jn * 7 + q];
                int jf = (j + 5 > last) ? last : j + 5;
                s1n = srcp[jf];
            }
        }
    }

    ush* tp = T + (size_t)(n - n0) * TLD + lane * 2;
#pragma unroll
    for (int k = 0; k < KK; k++) {
        *(unsigned*)(tp + (size_t)k * 128) = pack2bf(acc[k][0], acc[k][1]);
    }
}

// ---------------------------------------------------------------------------
// gemm2 v5: out[n,o] = [T_row(3456) | act_row(128)] . Wall(3584x128) + bias
// 512 threads / 8 waves, ONE m-tile per block -> 625 blocks = ~4.9 waves/SIMD
// for latency hiding. Wave owns 14 k-steps; the k-loop is FULLY UNROLLED
// (static indices) so the compiler hoists the independent A/B loads into a
// deep software pipeline. Cross-wave reduce via LDS in two 64-col passes.
// ---------------------------------------------------------------------------
__global__ __launch_bounds__(512) void gemm2_kernel(
    const ush* __restrict__ T, const ush* __restrict__ act,
    const short* __restrict__ Wh, const float* __restrict__ bias,
    ush* __restrict__ actout, float* __restrict__ fout,
    int n0, int relu)
{
    __shared__ float S[512][17];
    int lane = threadIdx.x & 63;
    int wave = threadIdx.x >> 6;
    int mtr = blockIdx.x;

    v4f acc[8];
#pragma unroll
    for (int nt = 0; nt < 8; nt++) acc[nt] = (v4f){0.f, 0.f, 0.f, 0.f};

    int arow = mtr * 16 + (lane & 15);           // chunk-local row
    int sub  = (lane >> 4) & 3;
    const ush* tp = T + (size_t)arow * TLD + sub * 8;
    const ush* ap = act + (size_t)(n0 + arow) * 128 + sub * 8;

    int ks0 = wave * (KSTEPS / 8);
#pragma unroll
    for (int i = 0; i < KSTEPS / 8; i++) {
        int ks = ks0 + i;
        v8s a = (ks < KK * 4) ? *(const v8s*)(tp + ks * 32)
                              : *(const v8s*)(ap + (ks - KK * 4) * 32);
        const short* wb = Wh + (size_t)ks * 4096 + (size_t)lane * 8;
#pragma unroll
        for (int nt = 0; nt < 8; nt++) {
            v8s b = *(const v8s*)(wb + (size_t)nt * 512);
            acc[nt] = __builtin_amdgcn_mfma_f32_16x16x32_bf16(a, b, acc[nt], 0, 0, 0);
        }
    }

    // cross-wave reduce + epilogue, two 64-column passes
    int r  = threadIdx.x >> 5;                 // output row in m-tile 0..15
    int cl = (threadIdx.x & 31) * 2;           // col pair within 64-col pass
    int row = n0 + mtr * 16 + r;
#pragma unroll
    for (int p = 0; p < 2; p++) {
        __syncthreads();
#pragma unroll
        for (int q = 0; q < 16; q++) S[threadIdx.x][q] = acc[p * 4 + (q >> 2)][q & 3];
        __syncthreads();
        float v[2];
#pragma unroll
        for (int h = 0; h < 2; h++) {
            int c = p * 64 + cl + h;               // global output column
            int ln  = (c & 15) + 16 * (r >> 2);    // source lane of C-frag
            int idx = (((c & 63) >> 4) << 2) + (r & 3);
            float s = 0.f;
#pragma unroll
            for (int w = 0; w < 8; w++) s += S[w * 64 + ln][idx];
            s += bias[c];
            if (relu) s = fmaxf(s, 0.f);
            v[h] = s;
        }
        int c0 = p * 64 + cl;
        if (actout) {
            *(unsigned*)(actout + (size_t)row * 128 + c0) = pack2bf(v[0], v[1]);
        } else {
            float2 f2; f2.x = v[0]; f2.y = v[1];
            *(float2*)(fout + (size_t)row * 128 + c0) = f2;
        }
    }
}

// ---------------------------------------------------------------------------
extern "C" void kernel_launch(void* const* d_in, const int* in_sizes, int n_in,
                              void* d_out, int out_size, void* d_ws, size_t ws_size,
                              hipStream_t stream) {
    const float* x   = (const float*)d_in[0];
    const void*  eix = d_in[1];
    const float* ea  = (const float*)d_in[2];
    const float* Wp1 = (const float*)d_in[3];
    const float* bp1 = (const float*)d_in[4];
    const float* Wp2 = (const float*)d_in[5];
    const float* bp2 = (const float*)d_in[6];
    const float* W[3]  = {(const float*)d_in[7],  (const float*)d_in[10], (const float*)d_in[13]};
    const float* Wr[3] = {(const float*)d_in[8],  (const float*)d_in[11], (const float*)d_in[14]};
    const float* b[3]  = {(const float*)d_in[9],  (const float*)d_in[12], (const float*)d_in[15]};
    float* out = (float*)d_out;

    char* ws = (char*)d_ws;
    size_t off = 0;
    auto walloc = [&](size_t bytes) -> void* {
        void* p = ws + off;
        off = (off + bytes + 255) & ~(size_t)255;
        return p;
    };
    int*    flag    = (int*)   walloc(sizeof(int));
    int*    e32     = (int*)   walloc(sizeof(int) * 2 * E_EDGES);
    float4* fb      = (float4*)walloc(sizeof(float4) * (size_t)E_EDGES);
    int*    srcp    = (int*)   walloc(sizeof(int) * E_EDGES);
    int*    eperm   = (int*)   walloc(sizeof(int) * E_EDGES);
    float*  w28p    = (float*) walloc(sizeof(float) * (size_t)E_EDGES * WLD);
    int*    histcur = (int*)   walloc(sizeof(int) * (size_t)N_NODES * 2);
    int*    rowptr  = (int*)   walloc(sizeof(int) * (N_NODES + 1));
    ush*    xb      = (ush*)   walloc(sizeof(ush) * (size_t)N_NODES * 128);
    ush*    a1      = (ush*)   walloc(sizeof(ush) * (size_t)N_NODES * 128);
    ush*    a2      = (ush*)   walloc(sizeof(ush) * (size_t)N_NODES * 128);
    short*  Wh3     = (short*) walloc(sizeof(short) * (size_t)3 * NB * 128 * 128);

    // Runtime chunk-size fallback: T chunk must fit in the remaining ws.
    // 20000 % chunk_n == 0 and chunk_n % 16 == 0 for all candidates.
    int chunk_n = 10000;
    {
        const int cand[3] = {10000, 4000, 2000};
        for (int i = 0; i < 3; i++) {
            size_t need = (size_t)cand[i] * TLD * sizeof(ush);
            chunk_n = cand[i];
            if (off + need <= ws_size) break;
        }
    }
    ush* T = (ush*)walloc((size_t)chunk_n * TLD * sizeof(ush));

    int* srcv = e32;
    int* dstv = e32 + E_EDGES;
    int* hist   = histcur;
    int* cursor = histcur + N_NODES;

    detect_kernel<<<1, 1024, 0, stream>>>((const unsigned int*)eix, flag);
    decode_edges<<<(2 * E_EDGES + 255) / 256, 256, 0, stream>>>(eix, flag, e32, 2 * E_EDGES);
    edge_basis<<<(E_EDGES + 255) / 256, 256, 0, stream>>>(ea, Wp1, bp1, Wp2, bp2, fb);

    // CSR binned by dst; built once, reused across 3 layers
    zero_int<<<(N_NODES * 2 + 255) / 256, 256, 0, stream>>>(histcur, N_NODES * 2);
    hist_kernel<<<(E_EDGES + 255) / 256, 256, 0, stream>>>(dstv, hist);
    scan_kernel<<<1, 256, 0, stream>>>(hist, rowptr, N_NODES);
    perm_kernel<<<(E_EDGES + 255) / 256, 256, 0, stream>>>(dstv, rowptr, cursor, eperm);
    pack_w27<<<(E_EDGES + 255) / 256, 256, 0, stream>>>(eperm, srcv, fb, srcp, w28p);

    packW3_kernel<<<(3 * NB * 4 * 8 * 64 + 255) / 256, 256, 0, stream>>>(
        W[0], Wr[0], W[1], Wr[1], W[2], Wr[2], Wh3);
    conv_xb<<<(N_NODES * CIN / 4 + 255) / 256, 256, 0, stream>>>(x, xb);

    const ush* actin = xb;
    for (int l = 0; l < 3; l++) {
        const short* Wh = Wh3 + (size_t)l * NB * 128 * 128;
        ush* actout = (l == 0) ? a1 : (l == 1) ? a2 : nullptr;
        for (int n0 = 0; n0 < N_NODES; n0 += chunk_n) {
            int cn = (n0 + chunk_n <= N_NODES) ? chunk_n : (N_NODES - n0);
            int nmt = cn / 16;
            accumT_kernel<<<cn, 64, 0, stream>>>(actin, rowptr, srcp, w28p, T, n0);
            gemm2_kernel<<<nmt, 512, 0, stream>>>(
                T, actin, Wh, b[l], actout, (l == 2) ? out : nullptr,
                n0, (l < 2) ? 1 : 0);
        }
        if (l == 0) actin = a1; else if (l == 1) actin = a2;
    }
}